// Round 12
// baseline (230.381 us; speedup 1.0000x reference)
//
#include <hip/hip_runtime.h>

static constexpr int NN  = 100000;   // nodes
static constexpr int NE  = 1600000;  // edges
static constexpr int NG  = 1000;     // graphs
static constexpr int D   = 64;       // D_IN = D_HID
static constexpr int DH  = 32;       // head hidden
static constexpr int DO  = 8;        // out dim
static constexpr int BKT = 128;      // nodes per bucket (7 bits)
static constexpr int NBK = (NN + BKT - 1) / BKT;     // 782
static constexpr int CHUNK = 2048;                   // edges per chunk block
static constexpr int NCH = (NE + CHUNK - 1) / CHUNK; // 782

typedef __attribute__((ext_vector_type(8))) short bf16x8;
typedef __attribute__((ext_vector_type(4))) float f32x4;

// ---- bf16 helpers (bit-level; values here are never NaN/inf) ----
__device__ __forceinline__ float b2f(unsigned short u) {
    return __uint_as_float(((unsigned int)u) << 16);
}
__device__ __forceinline__ unsigned short f2b(float f) {   // round-to-nearest-even
    unsigned int u = __float_as_uint(f);
    u += 0x7FFFu + ((u >> 16) & 1u);
    return (unsigned short)(u >> 16);
}
__device__ __forceinline__ uint4 pack8(const unsigned short* h) {
    uint4 u;
    u.x = (unsigned)h[0] | ((unsigned)h[1] << 16);
    u.y = (unsigned)h[2] | ((unsigned)h[3] << 16);
    u.z = (unsigned)h[4] | ((unsigned)h[5] << 16);
    u.w = (unsigned)h[6] | ((unsigned)h[7] << 16);
    return u;
}

// per-chunk LDS histogram of dst buckets -> count matrix (no global atomics)
__global__ __launch_bounds__(512) void
k_hist(const int* __restrict__ dst, int* __restrict__ cntmat) {
    __shared__ int lcnt[NBK];
    int t = threadIdx.x;
    long base = (long)blockIdx.x * CHUNK;
    for (int b = t; b < NBK; b += 512) lcnt[b] = 0;
    __syncthreads();
#pragma unroll
    for (int j = 0; j < 4; ++j) {
        long i = base + j * 512 + t;
        if (i < NE) atomicAdd(&lcnt[dst[i] >> 7], 1);   // LDS int atomic
    }
    __syncthreads();
    for (int b = t; b < NBK; b += 512)
        cntmat[blockIdx.x * NBK + b] = lcnt[b];
}

// fused: per-bucket scan over chunks (cntmat -> local exclusive prefix)
// + bucket total to bsum. k_bin adds boffs[b] itself.
__global__ __launch_bounds__(1024) void
k_colsum_rowscan(int* __restrict__ cntmat, int* __restrict__ bsum) {
    __shared__ int s[1024];
    int b = blockIdx.x, t = threadIdx.x;
    int v = (t < NCH) ? cntmat[t * NBK + b] : 0;
    s[t] = v;
    __syncthreads();
    for (int o = 1; o < 1024; o <<= 1) {
        int a = (t >= o) ? s[t - o] : 0;
        __syncthreads();
        s[t] += a;
        __syncthreads();
    }
    if (t < NCH) cntmat[t * NBK + b] = s[t] - v;   // local exclusive prefix
    if (t == 0) bsum[b] = s[1023];                 // bucket total
}

// fused: block 0 = exclusive scan of NBK bucket totals -> boffs (+NE sentinel);
// blocks 1,2 = split W into transposed bf16 hi/lo (W1, W2).
__global__ __launch_bounds__(1024) void
k_scan_prepw(const int* __restrict__ bsum, int* __restrict__ boffs,
             const float* __restrict__ W1, const float* __restrict__ W2,
             unsigned short* __restrict__ wtbuf) {
    int t = threadIdx.x;
    if (blockIdx.x == 0) {
        __shared__ int s[1024];
        int v = (t < NBK) ? bsum[t] : 0;
        s[t] = v;
        __syncthreads();
        for (int o = 1; o < 1024; o <<= 1) {
            int a = (t >= o) ? s[t - o] : 0;
            __syncthreads();
            s[t] += a;
            __syncthreads();
        }
        if (t < NBK) boffs[t] = s[t] - v;
        if (t == 0) boffs[NBK] = NE;
    } else if (t < 256) {
        const float* W = (blockIdx.x == 2) ? W2 : W1;
        unsigned short* WtHi = wtbuf + (size_t)(blockIdx.x - 1) * 8192;
        unsigned short* WtLo = WtHi + 4096;
        int n = t >> 2, k0 = (t & 3) * 16;
        unsigned short hi[16], lo[16];
#pragma unroll
        for (int i = 0; i < 16; ++i) {
            float v = W[(k0 + i) * 64 + n];
            hi[i] = f2b(v);
            lo[i] = f2b(v - b2f(hi[i]));
        }
        ((uint4*)WtHi)[n * 8 + (t & 3) * 2]     = pack8(hi);
        ((uint4*)WtHi)[n * 8 + (t & 3) * 2 + 1] = pack8(hi + 8);
        ((uint4*)WtLo)[n * 8 + (t & 3) * 2]     = pack8(lo);
        ((uint4*)WtLo)[n * 8 + (t & 3) * 2 + 1] = pack8(lo + 8);
    }
}

// binning with precomputed bases (local prefix + boffs): zero global atomics.
__global__ __launch_bounds__(512) void
k_bin(const int* __restrict__ src, const int* __restrict__ dst,
      const int* __restrict__ cntmat, const int* __restrict__ boffs,
      int* __restrict__ ebuf) {
    __shared__ int lcnt[NBK];
    __shared__ int lbase[NBK];
    int t = threadIdx.x;
    long base = (long)blockIdx.x * CHUNK;
    for (int b = t; b < NBK; b += 512) lcnt[b] = 0;
    __syncthreads();
    int pk[4], bk[4], of[4];
#pragma unroll
    for (int j = 0; j < 4; ++j) {
        long i = base + j * 512 + t;
        if (i < NE) {
            int d = dst[i];
            bk[j] = d >> 7;
            pk[j] = src[i] * BKT + (d & (BKT - 1));
            of[j] = atomicAdd(&lcnt[bk[j]], 1);
        } else bk[j] = -1;
    }
    __syncthreads();
    for (int b = t; b < NBK; b += 512)
        lbase[b] = cntmat[blockIdx.x * NBK + b] + boffs[b];
    __syncthreads();
#pragma unroll
    for (int j = 0; j < 4; ++j)
        if (bk[j] >= 0) ebuf[lbase[bk[j]] + of[j]] = pk[j];
}

// per-bucket: LDS hist of local idx -> rowptr/dinv, exact CSR scatter,
// plus degree-sorted permutation within each 64-node group (invalid -> last).
__global__ __launch_bounds__(512) void
k_csrdeg(const int* __restrict__ boffs, const int* __restrict__ ebuf,
         int* __restrict__ rowptr, float* __restrict__ dinv, int* __restrict__ csr,
         int* __restrict__ perm) {
    __shared__ int hist[BKT];
    __shared__ int sc[BKT];
    __shared__ int lcur[BKT];
    int b = blockIdx.x, t = threadIdx.x;
    if (t < BKT) hist[t] = 0;
    __syncthreads();
    int beg = boffs[b], end = boffs[b + 1];
    for (int e = beg + t; e < end; e += 512)
        atomicAdd(&hist[ebuf[e] & (BKT - 1)], 1);
    __syncthreads();
    if (t < BKT) sc[t] = hist[t];
    __syncthreads();
    for (int o = 1; o < BKT; o <<= 1) {
        int a = (t < BKT && t >= o) ? sc[t - o] : 0;
        __syncthreads();
        if (t < BKT) sc[t] += a;
        __syncthreads();
    }
    int v0 = b * BKT;
    if (t < BKT) {
        int v = v0 + t;
        if (v < NN) {
            int excl = beg + sc[t] - hist[t];
            rowptr[v] = excl;
            dinv[v]   = rsqrtf((float)(hist[t] + 1));
            lcur[t]   = excl;
        }
        // degree rank within this node's 64-group (strict order by (key, idx))
        int base64 = t & 64;   // 0 or 64
        int key = (v < NN) ? hist[t] : 0x7fffffff;
        int rank = 0;
        for (int j = 0; j < 64; ++j) {
            int tj = base64 + j;
            int kj = (v0 + tj < NN) ? hist[tj] : 0x7fffffff;
            rank += (kj < key) || (kj == key && tj < t);
        }
        perm[v0 + base64 + rank] = v;
    }
    if (b == NBK - 1 && t == 0) rowptr[NN] = NE;
    __syncthreads();
    for (int e = beg + t; e < end; e += 512) {
        int p = ebuf[e];
        int slot = atomicAdd(&lcur[p & (BKT - 1)], 1);
        csr[slot] = p >> 7;
    }
}

// MFMA matmul: out[n][:] = bf16(dinv[n] * (A[n][:] @ W)), 64 nodes/block.
// Split-bf16: A@W = Ahi·Whi + Ahi·Wlo + Alo·Whi — ~f32 accurate (f32 A input).
__global__ __launch_bounds__(256) void
k_mm_mfma(const float* __restrict__ Ain, const unsigned short* __restrict__ wt,
          const float* __restrict__ dinv, uint4* __restrict__ out) {
    __shared__ unsigned short smem[4 * 64 * 72];   // 36864 B
    unsigned short* Ahi  = smem;
    unsigned short* Alo  = smem + 4608;
    unsigned short* WtHi = smem + 9216;
    unsigned short* WtLo = smem + 13824;
    int t = threadIdx.x;
    int r = t >> 2, cc = t & 3, c0 = cc * 16;
    long n0 = (long)blockIdx.x * 64;
    {   // stage Wt (hi/lo), coalesced
        const uint4* H = (const uint4*)wt;
        const uint4* L = (const uint4*)(wt + 4096);
        uint4* dh = (uint4*)&WtHi[r * 72 + c0];
        uint4* dl = (uint4*)&WtLo[r * 72 + c0];
        dh[0] = H[r * 8 + cc * 2]; dh[1] = H[r * 8 + cc * 2 + 1];
        dl[0] = L[r * 8 + cc * 2]; dl[1] = L[r * 8 + cc * 2 + 1];
    }
    {   // stage A (convert + split)
        long n = n0 + r; if (n >= NN) n = NN - 1;
        const float4* X = (const float4*)Ain;
        unsigned short hi[16], lo[16];
#pragma unroll
        for (int i = 0; i < 4; ++i) {
            float4 v = X[n * 16 + cc * 4 + i];
            float vv[4] = {v.x, v.y, v.z, v.w};
#pragma unroll
            for (int j = 0; j < 4; ++j) {
                unsigned short h = f2b(vv[j]);
                hi[i * 4 + j] = h;
                lo[i * 4 + j] = f2b(vv[j] - b2f(h));
            }
        }
        uint4* dh = (uint4*)&Ahi[r * 72 + c0];
        uint4* dl = (uint4*)&Alo[r * 72 + c0];
        dh[0] = pack8(hi); dh[1] = pack8(hi + 8);
        dl[0] = pack8(lo); dl[1] = pack8(lo + 8);
    }
    __syncthreads();
    int lane = t & 63, w = t >> 6;
    int q = lane >> 4, m = lane & 15;
    f32x4 acc[4] = {{0.f,0.f,0.f,0.f},{0.f,0.f,0.f,0.f},{0.f,0.f,0.f,0.f},{0.f,0.f,0.f,0.f}};
#pragma unroll
    for (int s = 0; s < 2; ++s) {
        int ko = s * 32 + q * 8;
        bf16x8 ah = *(const bf16x8*)&Ahi[(w * 16 + m) * 72 + ko];
        bf16x8 al = *(const bf16x8*)&Alo[(w * 16 + m) * 72 + ko];
#pragma unroll
        for (int c = 0; c < 4; ++c) {
            bf16x8 bh = *(const bf16x8*)&WtHi[(c * 16 + m) * 72 + ko];
            bf16x8 bl = *(const bf16x8*)&WtLo[(c * 16 + m) * 72 + ko];
            acc[c] = __builtin_amdgcn_mfma_f32_16x16x32_bf16(ah, bh, acc[c], 0, 0, 0);
            acc[c] = __builtin_amdgcn_mfma_f32_16x16x32_bf16(ah, bl, acc[c], 0, 0, 0);
            acc[c] = __builtin_amdgcn_mfma_f32_16x16x32_bf16(al, bh, acc[c], 0, 0, 0);
        }
    }
    __syncthreads();
    float* Ct = (float*)smem;   // 64 x 68 f32 tile (overlaps dead A/Wt)
#pragma unroll
    for (int c = 0; c < 4; ++c)
#pragma unroll
        for (int rr = 0; rr < 4; ++rr)
            Ct[(w * 16 + q * 4 + rr) * 68 + c * 16 + m] = acc[c][rr];
    __syncthreads();
    {
        long n = n0 + r;
        if (n < NN) {
            float dv = dinv[n];
            unsigned short ob[16];
#pragma unroll
            for (int i = 0; i < 4; ++i) {
                float4 v = *(const float4*)&Ct[r * 68 + c0 + i * 4];
                ob[i * 4 + 0] = f2b(v.x * dv); ob[i * 4 + 1] = f2b(v.y * dv);
                ob[i * 4 + 2] = f2b(v.z * dv); ob[i * 4 + 3] = f2b(v.w * dv);
            }
            out[n * 8 + cc * 2]     = pack8(ob);
            out[n * 8 + cc * 2 + 1] = pack8(ob + 8);
        }
    }
}

// Fused agg(layer1, relu) -> LDS h1 tile -> MFMA @ W2 -> g2.  64 nodes/block.
// Phase 1 processes nodes in degree-sorted order (perm within 64-groups).
__global__ __launch_bounds__(512) void
k_aggmm(const int* __restrict__ rowptr, const int* __restrict__ csr,
        const int* __restrict__ perm,
        const uint4* __restrict__ g4, const float* __restrict__ dinv,
        const float* __restrict__ bias, const unsigned short* __restrict__ wt,
        uint4* __restrict__ out) {
    __shared__ unsigned short smem[3 * 4608];   // Ahi | WtHi | WtLo (27648 B)
    unsigned short* Ahi  = smem;
    unsigned short* WtHi = smem + 4608;
    unsigned short* WtLo = smem + 9216;
    int t = threadIdx.x;
    long n0 = (long)blockIdx.x * 64;
    if (t < 256) {   // stage W2 (hi/lo)
        int r = t >> 2, cc = t & 3, c0 = cc * 16;
        const uint4* H = (const uint4*)wt;
        const uint4* L = (const uint4*)(wt + 4096);
        uint4* dh = (uint4*)&WtHi[r * 72 + c0];
        uint4* dl = (uint4*)&WtLo[r * 72 + c0];
        dh[0] = H[r * 8 + cc * 2]; dh[1] = H[r * 8 + cc * 2 + 1];
        dl[0] = L[r * 8 + cc * 2]; dl[1] = L[r * 8 + cc * 2 + 1];
    }
    // phase 1: aggregate 8 waves x 8 nodes (degree-sorted assignment)
    int lane = t & 63, w = t >> 6;
    int fg = lane & 7, slot = lane >> 3;
    int ln = w * 8 + slot;                 // local position 0..63
    int v = perm[n0 + ln];                 // node (within [n0, n0+64) by construction)
    bool valid = v < NN;
    int vc = valid ? v : NN - 1;
    int beg = rowptr[vc];
    int len = valid ? (rowptr[vc + 1] - beg) : 0;
    int lmax = len;
    lmax = max(lmax, __shfl_xor(lmax, 8));
    lmax = max(lmax, __shfl_xor(lmax, 16));
    lmax = max(lmax, __shfl_xor(lmax, 32));
    float acc[8];
    {
        uint4 sv = g4[(long)vc * 8 + fg];
        if (!valid) { sv.x = sv.y = sv.z = sv.w = 0u; }
        acc[0] = __uint_as_float(sv.x << 16); acc[1] = __uint_as_float(sv.x & 0xFFFF0000u);
        acc[2] = __uint_as_float(sv.y << 16); acc[3] = __uint_as_float(sv.y & 0xFFFF0000u);
        acc[4] = __uint_as_float(sv.z << 16); acc[5] = __uint_as_float(sv.z & 0xFFFF0000u);
        acc[6] = __uint_as_float(sv.w << 16); acc[7] = __uint_as_float(sv.w & 0xFFFF0000u);
    }
    for (int e = 0; e < lmax; e += 8) {
#pragma unroll
        for (int j = 0; j < 8; ++j) {
            int ee = e + j;
            float m = (ee < len) ? 1.f : 0.f;
            int idx = beg + ((ee < len) ? ee : 0);
            int srcn = csr[idx];
            uint4 a = g4[(long)srcn * 8 + fg];
            acc[0] += m * __uint_as_float(a.x << 16);
            acc[1] += m * __uint_as_float(a.x & 0xFFFF0000u);
            acc[2] += m * __uint_as_float(a.y << 16);
            acc[3] += m * __uint_as_float(a.y & 0xFFFF0000u);
            acc[4] += m * __uint_as_float(a.z << 16);
            acc[5] += m * __uint_as_float(a.z & 0xFFFF0000u);
            acc[6] += m * __uint_as_float(a.w << 16);
            acc[7] += m * __uint_as_float(a.w & 0xFFFF0000u);
        }
    }
    {
        float dv = dinv[vc];
        unsigned short ob[8];
#pragma unroll
        for (int k = 0; k < 8; ++k) {
            float x = fmaxf(acc[k] * dv + bias[fg * 8 + k], 0.f);   // h1 = relu(..)
            ob[k] = f2b(x);
        }
        *(uint4*)&Ahi[(v - (int)n0) * 72 + fg * 8] = pack8(ob);   // tile row = true local idx
    }
    __syncthreads();
    // phase 2: MFMA h1 @ W2 (8 waves: row strip = (w&3)*16, 2 col-blocks each)
    int q = lane >> 4, m = lane & 15;
    int rs = (w & 3) * 16;
    int cb0 = (w >> 2) * 2;
    f32x4 c2[2] = {{0.f,0.f,0.f,0.f},{0.f,0.f,0.f,0.f}};
#pragma unroll
    for (int s = 0; s < 2; ++s) {
        int ko = s * 32 + q * 8;
        bf16x8 ah = *(const bf16x8*)&Ahi[(rs + m) * 72 + ko];
#pragma unroll
        for (int c = 0; c < 2; ++c) {
            bf16x8 bh = *(const bf16x8*)&WtHi[((cb0 + c) * 16 + m) * 72 + ko];
            bf16x8 bl = *(const bf16x8*)&WtLo[((cb0 + c) * 16 + m) * 72 + ko];
            c2[c] = __builtin_amdgcn_mfma_f32_16x16x32_bf16(ah, bh, c2[c], 0, 0, 0);
            c2[c] = __builtin_amdgcn_mfma_f32_16x16x32_bf16(ah, bl, c2[c], 0, 0, 0);
        }
    }
    __syncthreads();
    float* Ct = (float*)smem;   // 64 x 68 f32 = 17408 B (overlaps dead A/Wt)
#pragma unroll
    for (int c = 0; c < 2; ++c)
#pragma unroll
        for (int rr = 0; rr < 4; ++rr)
            Ct[(rs + q * 4 + rr) * 68 + (cb0 + c) * 16 + m] = c2[c][rr];
    __syncthreads();
    {
        int r = t >> 3, c8 = (t & 7) * 8;
        long n = n0 + r;
        if (n < NN) {
            float dv = dinv[n];
            float4 a = *(const float4*)&Ct[r * 68 + c8];
            float4 b = *(const float4*)&Ct[r * 68 + c8 + 4];
            unsigned short ob[8] = {f2b(a.x * dv), f2b(a.y * dv), f2b(a.z * dv), f2b(a.w * dv),
                                    f2b(b.x * dv), f2b(b.y * dv), f2b(b.z * dv), f2b(b.w * dv)};
            out[n * 8 + (t & 7)] = pack8(ob);
        }
    }
}

// CSR pull aggregation on bf16 rows (layer 2, no relu), degree-sorted nodes.
__global__ __launch_bounds__(256) void
k_agg2(const int* __restrict__ rowptr, const int* __restrict__ csr,
       const int* __restrict__ perm,
       const uint4* __restrict__ g4, const float* __restrict__ dinv,
       const float* __restrict__ bias, uint4* __restrict__ out4) {
    int t = threadIdx.x;
    int lane = t & 63;
    int fg = lane & 7;
    int slot = lane >> 3;
    int wid = blockIdx.x * 4 + (t >> 6);
    int v = perm[wid * 8 + slot];   // positions 0..NN-1 hold valid nodes only
    int beg = rowptr[v];
    int len = rowptr[v + 1] - beg;
    int lmax = len;
    lmax = max(lmax, __shfl_xor(lmax, 8));
    lmax = max(lmax, __shfl_xor(lmax, 16));
    lmax = max(lmax, __shfl_xor(lmax, 32));
    float acc[8];
    {
        uint4 sv = g4[(long)v * 8 + fg];
        acc[0] = __uint_as_float(sv.x << 16); acc[1] = __uint_as_float(sv.x & 0xFFFF0000u);
        acc[2] = __uint_as_float(sv.y << 16); acc[3] = __uint_as_float(sv.y & 0xFFFF0000u);
        acc[4] = __uint_as_float(sv.z << 16); acc[5] = __uint_as_float(sv.z & 0xFFFF0000u);
        acc[6] = __uint_as_float(sv.w << 16); acc[7] = __uint_as_float(sv.w & 0xFFFF0000u);
    }
    for (int e = 0; e < lmax; e += 8) {
#pragma unroll
        for (int j = 0; j < 8; ++j) {
            int ee = e + j;
            float m = (ee < len) ? 1.f : 0.f;
            int idx = beg + ((ee < len) ? ee : 0);
            int srcn = csr[idx];
            uint4 a = g4[(long)srcn * 8 + fg];
            acc[0] += m * __uint_as_float(a.x << 16);
            acc[1] += m * __uint_as_float(a.x & 0xFFFF0000u);
            acc[2] += m * __uint_as_float(a.y << 16);
            acc[3] += m * __uint_as_float(a.y & 0xFFFF0000u);
            acc[4] += m * __uint_as_float(a.z << 16);
            acc[5] += m * __uint_as_float(a.z & 0xFFFF0000u);
            acc[6] += m * __uint_as_float(a.w << 16);
            acc[7] += m * __uint_as_float(a.w & 0xFFFF0000u);
        }
    }
    float dv = dinv[v];
    unsigned short ob[8];
#pragma unroll
    for (int k = 0; k < 8; ++k)
        ob[k] = f2b(acc[k] * dv + bias[fg * 8 + k]);
    out4[(long)v * 8 + fg] = pack8(ob);
}

// fused mean-pool + MLP head, one wave per graph, zero atomics (batch sorted)
__global__ void k_poolhead(const unsigned short* __restrict__ h,
                           const int* __restrict__ batch,
                           const float* __restrict__ lw1, const float* __restrict__ lb1,
                           const float* __restrict__ lw2, const float* __restrict__ lb2,
                           float* __restrict__ out) {
    __shared__ float pl[D];
    __shared__ float z[DH];
    int g = blockIdx.x;
    int t = threadIdx.x;  // 64, lane = dim
    int lo = 0, hi = NN;
    while (lo < hi) { int m = (lo + hi) >> 1; if (batch[m] < g) lo = m + 1; else hi = m; }
    int lb = lo;
    hi = NN;
    while (lo < hi) { int m = (lo + hi) >> 1; if (batch[m] < g + 1) lo = m + 1; else hi = m; }
    int ub = lo;
    float s = 0.f;
    int n = lb;
    for (; n + 4 <= ub; n += 4) {
        float a0 = b2f(h[(long)(n + 0) * D + t]);
        float a1 = b2f(h[(long)(n + 1) * D + t]);
        float a2 = b2f(h[(long)(n + 2) * D + t]);
        float a3 = b2f(h[(long)(n + 3) * D + t]);
        s += a0 + a1 + a2 + a3;
    }
    for (; n < ub; ++n) s += b2f(h[(long)n * D + t]);
    pl[t] = s / fmaxf((float)(ub - lb), 1.0f);
    __syncthreads();
    if (t < DH) {
        float a = lb1[t];
#pragma unroll
        for (int k = 0; k < D; ++k) a += pl[k] * lw1[k * DH + t];
        z[t] = fmaxf(a, 0.f);
    }
    __syncthreads();
    if (t < DO) {
        float a = lb2[t];
#pragma unroll
        for (int j = 0; j < DH; ++j) a += z[j] * lw2[j * DO + t];
        out[g * DO + t] = a;
    }
}

extern "C" void kernel_launch(void* const* d_in, const int* in_sizes, int n_in,
                              void* d_out, int out_size, void* d_ws, size_t ws_size,
                              hipStream_t stream) {
    const float* x    = (const float*)d_in[0];
    const int*   ei   = (const int*)  d_in[1];
    const int*   batch= (const int*)  d_in[2];
    const float* W1   = (const float*)d_in[3];
    const float* b1   = (const float*)d_in[4];
    const float* W2   = (const float*)d_in[5];
    const float* b2   = (const float*)d_in[6];
    const float* lw1  = (const float*)d_in[7];
    const float* lb1  = (const float*)d_in[8];
    const float* lw2  = (const float*)d_in[9];
    const float* lb2  = (const float*)d_in[10];
    float* out = (float*)d_out;

    const int* srcv = ei;        // edge_index[0]
    const int* dstv = ei + NE;   // edge_index[1]

    char* ws = (char*)d_ws;
    size_t off = 0;
    auto alloc = [&](size_t bytes) {
        void* p = ws + off;
        off = (off + bytes + 255) & ~(size_t)255;
        return p;
    };
    int*   cntmat = (int*)  alloc((size_t)NCH * NBK * 4);  // 2.45 MB
    int*   bsum   = (int*)  alloc((size_t)NBK * 4);
    int*   boffs  = (int*)  alloc((size_t)(NBK + 1) * 4);
    int*   rowptr = (int*)  alloc((size_t)(NN + 1) * 4);
    int*   perm   = (int*)  alloc((size_t)NBK * BKT * 4);  // 100096 entries
    int*   csr    = (int*)  alloc((size_t)NE * 4);         // 6.4 MB
    float* dinv   = (float*)alloc((size_t)NN * 4);
    unsigned short* wtbuf = (unsigned short*)alloc((size_t)4 * 4096 * 2);  // 32 KB
    unsigned short* bufA = (unsigned short*)alloc((size_t)NN * D * 2);    // 12.8 MB
    unsigned short* bufB = (unsigned short*)alloc((size_t)NN * D * 2);    // 12.8 MB
    int*   ebuf   = (int*)bufA;  // binning scratch; dead before bufA first written

    k_hist          <<<NCH, 512, 0, stream>>>(dstv, cntmat);
    k_colsum_rowscan<<<NBK, 1024, 0, stream>>>(cntmat, bsum);
    k_scan_prepw    <<<3, 1024, 0, stream>>>(bsum, boffs, W1, W2, wtbuf);
    k_bin           <<<NCH, 512, 0, stream>>>(srcv, dstv, cntmat, boffs, ebuf);
    k_csrdeg        <<<NBK, 512, 0, stream>>>(boffs, ebuf, rowptr, dinv, csr, perm);

    const int MMB = (NN + 63) / 64;   // 1563

    // layer 1 mm: g1 = bf16((x @ W1) * dinv) -> bufA
    k_mm_mfma<<<MMB, 256, 0, stream>>>(x, wtbuf, dinv, (uint4*)bufA);
    // fused: h1 = relu(agg(g1)) (LDS tile) ; g2 = bf16((h1 @ W2) * dinv) -> bufB
    k_aggmm<<<MMB, 512, 0, stream>>>(rowptr, csr, perm, (const uint4*)bufA, dinv, b1,
                                     wtbuf + 8192, (uint4*)bufB);
    // layer 2 agg: h2 = agg(g2) -> bufA
    k_agg2<<<NN / 32, 256, 0, stream>>>(rowptr, csr, perm, (const uint4*)bufB, dinv, b2,
                                        (uint4*)bufA);
    k_poolhead<<<NG, 64, 0, stream>>>(bufA, batch, lw1, lb1, lw2, lb2, out);
}

// Round 13
// 226.498 us; speedup vs baseline: 1.0171x; 1.0171x over previous
//
#include <hip/hip_runtime.h>

static constexpr int NN  = 100000;   // nodes
static constexpr int NE  = 1600000;  // edges
static constexpr int NG  = 1000;     // graphs
static constexpr int D   = 64;       // D_IN = D_HID
static constexpr int DH  = 32;       // head hidden
static constexpr int DO  = 8;        // out dim
static constexpr int BKT = 128;      // nodes per bucket (7 bits)
static constexpr int NBK = (NN + BKT - 1) / BKT;     // 782
static constexpr int CHUNK = 4096;                   // edges per chunk block
static constexpr int NCH = (NE + CHUNK - 1) / CHUNK; // 391

typedef __attribute__((ext_vector_type(8))) short bf16x8;
typedef __attribute__((ext_vector_type(4))) float f32x4;

// ---- bf16 helpers (bit-level; values here are never NaN/inf) ----
__device__ __forceinline__ float b2f(unsigned short u) {
    return __uint_as_float(((unsigned int)u) << 16);
}
__device__ __forceinline__ unsigned short f2b(float f) {   // round-to-nearest-even
    unsigned int u = __float_as_uint(f);
    u += 0x7FFFu + ((u >> 16) & 1u);
    return (unsigned short)(u >> 16);
}
__device__ __forceinline__ uint4 pack8(const unsigned short* h) {
    uint4 u;
    u.x = (unsigned)h[0] | ((unsigned)h[1] << 16);
    u.y = (unsigned)h[2] | ((unsigned)h[3] << 16);
    u.z = (unsigned)h[4] | ((unsigned)h[5] << 16);
    u.w = (unsigned)h[6] | ((unsigned)h[7] << 16);
    return u;
}

// per-chunk LDS histogram of dst buckets -> count matrix (no global atomics)
__global__ __launch_bounds__(512) void
k_hist(const int* __restrict__ dst, int* __restrict__ cntmat) {
    __shared__ int lcnt[NBK];
    int t = threadIdx.x;
    long base = (long)blockIdx.x * CHUNK;
    for (int b = t; b < NBK; b += 512) lcnt[b] = 0;
    __syncthreads();
#pragma unroll
    for (int j = 0; j < 8; ++j) {
        long i = base + j * 512 + t;
        if (i < NE) atomicAdd(&lcnt[dst[i] >> 7], 1);   // LDS int atomic
    }
    __syncthreads();
    for (int b = t; b < NBK; b += 512)
        cntmat[blockIdx.x * NBK + b] = lcnt[b];
}

// fused: per-bucket scan over chunks (cntmat -> local exclusive prefix)
// + bucket total to bsum. k_bin adds boffs[b] itself.
__global__ __launch_bounds__(512) void
k_colsum_rowscan(int* __restrict__ cntmat, int* __restrict__ bsum) {
    __shared__ int s[512];
    int b = blockIdx.x, t = threadIdx.x;
    int v = (t < NCH) ? cntmat[t * NBK + b] : 0;
    s[t] = v;
    __syncthreads();
    for (int o = 1; o < 512; o <<= 1) {
        int a = (t >= o) ? s[t - o] : 0;
        __syncthreads();
        s[t] += a;
        __syncthreads();
    }
    if (t < NCH) cntmat[t * NBK + b] = s[t] - v;   // local exclusive prefix
    if (t == 0) bsum[b] = s[511];                  // bucket total
}

// fused: block 0 = exclusive scan of NBK bucket totals -> boffs (+NE sentinel);
// blocks 1,2 = split W into transposed bf16 hi/lo (W1, W2).
__global__ __launch_bounds__(1024) void
k_scan_prepw(const int* __restrict__ bsum, int* __restrict__ boffs,
             const float* __restrict__ W1, const float* __restrict__ W2,
             unsigned short* __restrict__ wtbuf) {
    int t = threadIdx.x;
    if (blockIdx.x == 0) {
        __shared__ int s[1024];
        int v = (t < NBK) ? bsum[t] : 0;
        s[t] = v;
        __syncthreads();
        for (int o = 1; o < 1024; o <<= 1) {
            int a = (t >= o) ? s[t - o] : 0;
            __syncthreads();
            s[t] += a;
            __syncthreads();
        }
        if (t < NBK) boffs[t] = s[t] - v;
        if (t == 0) boffs[NBK] = NE;
    } else if (t < 256) {
        const float* W = (blockIdx.x == 2) ? W2 : W1;
        unsigned short* WtHi = wtbuf + (size_t)(blockIdx.x - 1) * 8192;
        unsigned short* WtLo = WtHi + 4096;
        int n = t >> 2, k0 = (t & 3) * 16;
        unsigned short hi[16], lo[16];
#pragma unroll
        for (int i = 0; i < 16; ++i) {
            float v = W[(k0 + i) * 64 + n];
            hi[i] = f2b(v);
            lo[i] = f2b(v - b2f(hi[i]));
        }
        ((uint4*)WtHi)[n * 8 + (t & 3) * 2]     = pack8(hi);
        ((uint4*)WtHi)[n * 8 + (t & 3) * 2 + 1] = pack8(hi + 8);
        ((uint4*)WtLo)[n * 8 + (t & 3) * 2]     = pack8(lo);
        ((uint4*)WtLo)[n * 8 + (t & 3) * 2 + 1] = pack8(lo + 8);
    }
}

// binning with precomputed bases (local prefix + boffs): zero global atomics.
__global__ __launch_bounds__(512) void
k_bin(const int* __restrict__ src, const int* __restrict__ dst,
      const int* __restrict__ cntmat, const int* __restrict__ boffs,
      int* __restrict__ ebuf) {
    __shared__ int lcnt[NBK];
    __shared__ int lbase[NBK];
    int t = threadIdx.x;
    long base = (long)blockIdx.x * CHUNK;
    for (int b = t; b < NBK; b += 512) lcnt[b] = 0;
    __syncthreads();
    int pk[8], bk[8], of[8];
#pragma unroll
    for (int j = 0; j < 8; ++j) {
        long i = base + j * 512 + t;
        if (i < NE) {
            int d = dst[i];
            bk[j] = d >> 7;
            pk[j] = src[i] * BKT + (d & (BKT - 1));
            of[j] = atomicAdd(&lcnt[bk[j]], 1);
        } else bk[j] = -1;
    }
    __syncthreads();
    for (int b = t; b < NBK; b += 512)
        lbase[b] = cntmat[blockIdx.x * NBK + b] + boffs[b];
    __syncthreads();
#pragma unroll
    for (int j = 0; j < 8; ++j)
        if (bk[j] >= 0) ebuf[lbase[bk[j]] + of[j]] = pk[j];
}

// per-bucket: LDS histogram of local idx -> rowptr/dinv, then exact CSR scatter
__global__ __launch_bounds__(512) void
k_csrdeg(const int* __restrict__ boffs, const int* __restrict__ ebuf,
         int* __restrict__ rowptr, float* __restrict__ dinv, int* __restrict__ csr) {
    __shared__ int hist[BKT];
    __shared__ int sc[BKT];
    __shared__ int lcur[BKT];
    int b = blockIdx.x, t = threadIdx.x;
    if (t < BKT) hist[t] = 0;
    __syncthreads();
    int beg = boffs[b], end = boffs[b + 1];
    for (int e = beg + t; e < end; e += 512)
        atomicAdd(&hist[ebuf[e] & (BKT - 1)], 1);
    __syncthreads();
    if (t < BKT) sc[t] = hist[t];
    __syncthreads();
    for (int o = 1; o < BKT; o <<= 1) {
        int a = (t < BKT && t >= o) ? sc[t - o] : 0;
        __syncthreads();
        if (t < BKT) sc[t] += a;
        __syncthreads();
    }
    int v0 = b * BKT;
    if (t < BKT) {
        int v = v0 + t;
        if (v < NN) {
            int excl = beg + sc[t] - hist[t];
            rowptr[v] = excl;
            dinv[v]   = rsqrtf((float)(hist[t] + 1));
            lcur[t]   = excl;
        }
    }
    if (b == NBK - 1 && t == 0) rowptr[NN] = NE;
    __syncthreads();
    for (int e = beg + t; e < end; e += 512) {
        int p = ebuf[e];
        int slot = atomicAdd(&lcur[p & (BKT - 1)], 1);
        csr[slot] = p >> 7;
    }
}

// MFMA matmul: out[n][:] = bf16(dinv[n] * (A[n][:] @ W)), 64 nodes/block.
// Split-bf16: A@W = Ahi·Whi + Ahi·Wlo + Alo·Whi — ~f32 accurate (f32 A input).
__global__ __launch_bounds__(256) void
k_mm_mfma(const float* __restrict__ Ain, const unsigned short* __restrict__ wt,
          const float* __restrict__ dinv, uint4* __restrict__ out) {
    __shared__ unsigned short smem[4 * 64 * 72];   // 36864 B
    unsigned short* Ahi  = smem;
    unsigned short* Alo  = smem + 4608;
    unsigned short* WtHi = smem + 9216;
    unsigned short* WtLo = smem + 13824;
    int t = threadIdx.x;
    int r = t >> 2, cc = t & 3, c0 = cc * 16;
    long n0 = (long)blockIdx.x * 64;
    {   // stage Wt (hi/lo), coalesced
        const uint4* H = (const uint4*)wt;
        const uint4* L = (const uint4*)(wt + 4096);
        uint4* dh = (uint4*)&WtHi[r * 72 + c0];
        uint4* dl = (uint4*)&WtLo[r * 72 + c0];
        dh[0] = H[r * 8 + cc * 2]; dh[1] = H[r * 8 + cc * 2 + 1];
        dl[0] = L[r * 8 + cc * 2]; dl[1] = L[r * 8 + cc * 2 + 1];
    }
    {   // stage A (convert + split)
        long n = n0 + r; if (n >= NN) n = NN - 1;
        const float4* X = (const float4*)Ain;
        unsigned short hi[16], lo[16];
#pragma unroll
        for (int i = 0; i < 4; ++i) {
            float4 v = X[n * 16 + cc * 4 + i];
            float vv[4] = {v.x, v.y, v.z, v.w};
#pragma unroll
            for (int j = 0; j < 4; ++j) {
                unsigned short h = f2b(vv[j]);
                hi[i * 4 + j] = h;
                lo[i * 4 + j] = f2b(vv[j] - b2f(h));
            }
        }
        uint4* dh = (uint4*)&Ahi[r * 72 + c0];
        uint4* dl = (uint4*)&Alo[r * 72 + c0];
        dh[0] = pack8(hi); dh[1] = pack8(hi + 8);
        dl[0] = pack8(lo); dl[1] = pack8(lo + 8);
    }
    __syncthreads();
    int lane = t & 63, w = t >> 6;
    int q = lane >> 4, m = lane & 15;
    f32x4 acc[4] = {{0.f,0.f,0.f,0.f},{0.f,0.f,0.f,0.f},{0.f,0.f,0.f,0.f},{0.f,0.f,0.f,0.f}};
#pragma unroll
    for (int s = 0; s < 2; ++s) {
        int ko = s * 32 + q * 8;
        bf16x8 ah = *(const bf16x8*)&Ahi[(w * 16 + m) * 72 + ko];
        bf16x8 al = *(const bf16x8*)&Alo[(w * 16 + m) * 72 + ko];
#pragma unroll
        for (int c = 0; c < 4; ++c) {
            bf16x8 bh = *(const bf16x8*)&WtHi[(c * 16 + m) * 72 + ko];
            bf16x8 bl = *(const bf16x8*)&WtLo[(c * 16 + m) * 72 + ko];
            acc[c] = __builtin_amdgcn_mfma_f32_16x16x32_bf16(ah, bh, acc[c], 0, 0, 0);
            acc[c] = __builtin_amdgcn_mfma_f32_16x16x32_bf16(ah, bl, acc[c], 0, 0, 0);
            acc[c] = __builtin_amdgcn_mfma_f32_16x16x32_bf16(al, bh, acc[c], 0, 0, 0);
        }
    }
    __syncthreads();
    float* Ct = (float*)smem;   // 64 x 68 f32 tile (overlaps dead A/Wt)
#pragma unroll
    for (int c = 0; c < 4; ++c)
#pragma unroll
        for (int rr = 0; rr < 4; ++rr)
            Ct[(w * 16 + q * 4 + rr) * 68 + c * 16 + m] = acc[c][rr];
    __syncthreads();
    {
        long n = n0 + r;
        if (n < NN) {
            float dv = dinv[n];
            unsigned short ob[16];
#pragma unroll
            for (int i = 0; i < 4; ++i) {
                float4 v = *(const float4*)&Ct[r * 68 + c0 + i * 4];
                ob[i * 4 + 0] = f2b(v.x * dv); ob[i * 4 + 1] = f2b(v.y * dv);
                ob[i * 4 + 2] = f2b(v.z * dv); ob[i * 4 + 3] = f2b(v.w * dv);
            }
            out[n * 8 + cc * 2]     = pack8(ob);
            out[n * 8 + cc * 2 + 1] = pack8(ob + 8);
        }
    }
}

// Fused agg(layer1, relu) -> LDS h1 tile -> MFMA @ W2 -> g2.  64 nodes/block.
// csr indices fetched 8-at-a-time per slot via one coalesced load + shuffles.
__global__ __launch_bounds__(512) void
k_aggmm(const int* __restrict__ rowptr, const int* __restrict__ csr,
        const uint4* __restrict__ g4, const float* __restrict__ dinv,
        const float* __restrict__ bias, const unsigned short* __restrict__ wt,
        uint4* __restrict__ out) {
    __shared__ unsigned short smem[3 * 4608];   // Ahi | WtHi | WtLo (27648 B)
    unsigned short* Ahi  = smem;
    unsigned short* WtHi = smem + 4608;
    unsigned short* WtLo = smem + 9216;
    int t = threadIdx.x;
    long n0 = (long)blockIdx.x * 64;
    if (t < 256) {   // stage W2 (hi/lo)
        int r = t >> 2, cc = t & 3, c0 = cc * 16;
        const uint4* H = (const uint4*)wt;
        const uint4* L = (const uint4*)(wt + 4096);
        uint4* dh = (uint4*)&WtHi[r * 72 + c0];
        uint4* dl = (uint4*)&WtLo[r * 72 + c0];
        dh[0] = H[r * 8 + cc * 2]; dh[1] = H[r * 8 + cc * 2 + 1];
        dl[0] = L[r * 8 + cc * 2]; dl[1] = L[r * 8 + cc * 2 + 1];
    }
    // phase 1: aggregate 8 waves x 8 nodes
    int lane = t & 63, w = t >> 6;
    int fg = lane & 7, slot = lane >> 3;
    int ln = w * 8 + slot;                 // local node 0..63
    long v = n0 + ln;
    int vc = (v < NN) ? (int)v : NN - 1;
    int beg = rowptr[vc];
    int len = rowptr[vc + 1] - beg;
    if (v >= NN) len = 0;
    int lmax = len;
    lmax = max(lmax, __shfl_xor(lmax, 8));
    lmax = max(lmax, __shfl_xor(lmax, 16));
    lmax = max(lmax, __shfl_xor(lmax, 32));
    float acc[8];
    {
        uint4 sv = g4[(long)vc * 8 + fg];
        if (v >= NN) { sv.x = sv.y = sv.z = sv.w = 0u; }
        acc[0] = __uint_as_float(sv.x << 16); acc[1] = __uint_as_float(sv.x & 0xFFFF0000u);
        acc[2] = __uint_as_float(sv.y << 16); acc[3] = __uint_as_float(sv.y & 0xFFFF0000u);
        acc[4] = __uint_as_float(sv.z << 16); acc[5] = __uint_as_float(sv.z & 0xFFFF0000u);
        acc[6] = __uint_as_float(sv.w << 16); acc[7] = __uint_as_float(sv.w & 0xFFFF0000u);
    }
    for (int e = 0; e < lmax; e += 8) {
        // one coalesced csr load covers this slot's next 8 edges (lane fg -> edge e+fg)
        int ci = beg + e + fg;
        ci = (e + fg < len) ? ci : beg;
        int ec = csr[min(ci, NE - 1)];
#pragma unroll
        for (int j = 0; j < 8; ++j) {
            int ee = e + j;
            float m = (ee < len) ? 1.f : 0.f;
            int srcn = __shfl(ec, slot * 8 + j);   // broadcast edge j's index to the slot
            uint4 a = g4[(long)srcn * 8 + fg];
            acc[0] += m * __uint_as_float(a.x << 16);
            acc[1] += m * __uint_as_float(a.x & 0xFFFF0000u);
            acc[2] += m * __uint_as_float(a.y << 16);
            acc[3] += m * __uint_as_float(a.y & 0xFFFF0000u);
            acc[4] += m * __uint_as_float(a.z << 16);
            acc[5] += m * __uint_as_float(a.z & 0xFFFF0000u);
            acc[6] += m * __uint_as_float(a.w << 16);
            acc[7] += m * __uint_as_float(a.w & 0xFFFF0000u);
        }
    }
    {
        float dv = dinv[vc];
        unsigned short ob[8];
#pragma unroll
        for (int k = 0; k < 8; ++k) {
            float x = fmaxf(acc[k] * dv + bias[fg * 8 + k], 0.f);   // h1 = relu(..)
            ob[k] = f2b(x);
        }
        *(uint4*)&Ahi[ln * 72 + fg * 8] = pack8(ob);
    }
    __syncthreads();
    // phase 2: MFMA h1 @ W2 (8 waves: row strip = (w&3)*16, 2 col-blocks each)
    int q = lane >> 4, m = lane & 15;
    int rs = (w & 3) * 16;
    int cb0 = (w >> 2) * 2;
    f32x4 c2[2] = {{0.f,0.f,0.f,0.f},{0.f,0.f,0.f,0.f}};
#pragma unroll
    for (int s = 0; s < 2; ++s) {
        int ko = s * 32 + q * 8;
        bf16x8 ah = *(const bf16x8*)&Ahi[(rs + m) * 72 + ko];
#pragma unroll
        for (int c = 0; c < 2; ++c) {
            bf16x8 bh = *(const bf16x8*)&WtHi[((cb0 + c) * 16 + m) * 72 + ko];
            bf16x8 bl = *(const bf16x8*)&WtLo[((cb0 + c) * 16 + m) * 72 + ko];
            c2[c] = __builtin_amdgcn_mfma_f32_16x16x32_bf16(ah, bh, c2[c], 0, 0, 0);
            c2[c] = __builtin_amdgcn_mfma_f32_16x16x32_bf16(ah, bl, c2[c], 0, 0, 0);
        }
    }
    __syncthreads();
    float* Ct = (float*)smem;   // 64 x 68 f32 = 17408 B (overlaps dead A/Wt)
#pragma unroll
    for (int c = 0; c < 2; ++c)
#pragma unroll
        for (int rr = 0; rr < 4; ++rr)
            Ct[(rs + q * 4 + rr) * 68 + (cb0 + c) * 16 + m] = c2[c][rr];
    __syncthreads();
    {
        int r = t >> 3, c8 = (t & 7) * 8;
        long n = n0 + r;
        if (n < NN) {
            float dv = dinv[n];
            float4 a = *(const float4*)&Ct[r * 68 + c8];
            float4 b = *(const float4*)&Ct[r * 68 + c8 + 4];
            unsigned short ob[8] = {f2b(a.x * dv), f2b(a.y * dv), f2b(a.z * dv), f2b(a.w * dv),
                                    f2b(b.x * dv), f2b(b.y * dv), f2b(b.z * dv), f2b(b.w * dv)};
            out[n * 8 + (t & 7)] = pack8(ob);
        }
    }
}

// CSR pull aggregation on bf16 rows (layer 2, no relu), shuffle-fed csr.
__global__ __launch_bounds__(256) void
k_agg2(const int* __restrict__ rowptr, const int* __restrict__ csr,
       const uint4* __restrict__ g4, const float* __restrict__ dinv,
       const float* __restrict__ bias, uint4* __restrict__ out4) {
    int t = threadIdx.x;
    int lane = t & 63;
    int fg = lane & 7;
    int slot = lane >> 3;
    int wid = blockIdx.x * 4 + (t >> 6);
    int v = wid * 8 + slot;      // 12500 * 8 == NN exactly
    int beg = rowptr[v];
    int len = rowptr[v + 1] - beg;
    int lmax = len;
    lmax = max(lmax, __shfl_xor(lmax, 8));
    lmax = max(lmax, __shfl_xor(lmax, 16));
    lmax = max(lmax, __shfl_xor(lmax, 32));
    float acc[8];
    {
        uint4 sv = g4[(long)v * 8 + fg];
        acc[0] = __uint_as_float(sv.x << 16); acc[1] = __uint_as_float(sv.x & 0xFFFF0000u);
        acc[2] = __uint_as_float(sv.y << 16); acc[3] = __uint_as_float(sv.y & 0xFFFF0000u);
        acc[4] = __uint_as_float(sv.z << 16); acc[5] = __uint_as_float(sv.z & 0xFFFF0000u);
        acc[6] = __uint_as_float(sv.w << 16); acc[7] = __uint_as_float(sv.w & 0xFFFF0000u);
    }
    for (int e = 0; e < lmax; e += 8) {
        int ci = beg + e + fg;
        ci = (e + fg < len) ? ci : beg;
        int ec = csr[min(ci, NE - 1)];
#pragma unroll
        for (int j = 0; j < 8; ++j) {
            int ee = e + j;
            float m = (ee < len) ? 1.f : 0.f;
            int srcn = __shfl(ec, slot * 8 + j);
            uint4 a = g4[(long)srcn * 8 + fg];
            acc[0] += m * __uint_as_float(a.x << 16);
            acc[1] += m * __uint_as_float(a.x & 0xFFFF0000u);
            acc[2] += m * __uint_as_float(a.y << 16);
            acc[3] += m * __uint_as_float(a.y & 0xFFFF0000u);
            acc[4] += m * __uint_as_float(a.z << 16);
            acc[5] += m * __uint_as_float(a.z & 0xFFFF0000u);
            acc[6] += m * __uint_as_float(a.w << 16);
            acc[7] += m * __uint_as_float(a.w & 0xFFFF0000u);
        }
    }
    float dv = dinv[v];
    unsigned short ob[8];
#pragma unroll
    for (int k = 0; k < 8; ++k)
        ob[k] = f2b(acc[k] * dv + bias[fg * 8 + k]);
    out4[(long)v * 8 + fg] = pack8(ob);
}

// fused mean-pool + MLP head, one wave per graph, zero atomics (batch sorted)
__global__ void k_poolhead(const unsigned short* __restrict__ h,
                           const int* __restrict__ batch,
                           const float* __restrict__ lw1, const float* __restrict__ lb1,
                           const float* __restrict__ lw2, const float* __restrict__ lb2,
                           float* __restrict__ out) {
    __shared__ float pl[D];
    __shared__ float z[DH];
    int g = blockIdx.x;
    int t = threadIdx.x;  // 64, lane = dim
    int lo = 0, hi = NN;
    while (lo < hi) { int m = (lo + hi) >> 1; if (batch[m] < g) lo = m + 1; else hi = m; }
    int lb = lo;
    hi = NN;
    while (lo < hi) { int m = (lo + hi) >> 1; if (batch[m] < g + 1) lo = m + 1; else hi = m; }
    int ub = lo;
    float s = 0.f;
    int n = lb;
    for (; n + 4 <= ub; n += 4) {
        float a0 = b2f(h[(long)(n + 0) * D + t]);
        float a1 = b2f(h[(long)(n + 1) * D + t]);
        float a2 = b2f(h[(long)(n + 2) * D + t]);
        float a3 = b2f(h[(long)(n + 3) * D + t]);
        s += a0 + a1 + a2 + a3;
    }
    for (; n < ub; ++n) s += b2f(h[(long)n * D + t]);
    pl[t] = s / fmaxf((float)(ub - lb), 1.0f);
    __syncthreads();
    if (t < DH) {
        float a = lb1[t];
#pragma unroll
        for (int k = 0; k < D; ++k) a += pl[k] * lw1[k * DH + t];
        z[t] = fmaxf(a, 0.f);
    }
    __syncthreads();
    if (t < DO) {
        float a = lb2[t];
#pragma unroll
        for (int j = 0; j < DH; ++j) a += z[j] * lw2[j * DO + t];
        out[g * DO + t] = a;
    }
}

extern "C" void kernel_launch(void* const* d_in, const int* in_sizes, int n_in,
                              void* d_out, int out_size, void* d_ws, size_t ws_size,
                              hipStream_t stream) {
    const float* x    = (const float*)d_in[0];
    const int*   ei   = (const int*)  d_in[1];
    const int*   batch= (const int*)  d_in[2];
    const float* W1   = (const float*)d_in[3];
    const float* b1   = (const float*)d_in[4];
    const float* W2   = (const float*)d_in[5];
    const float* b2   = (const float*)d_in[6];
    const float* lw1  = (const float*)d_in[7];
    const float* lb1  = (const float*)d_in[8];
    const float* lw2  = (const float*)d_in[9];
    const float* lb2  = (const float*)d_in[10];
    float* out = (float*)d_out;

    const int* srcv = ei;        // edge_index[0]
    const int* dstv = ei + NE;   // edge_index[1]

    char* ws = (char*)d_ws;
    size_t off = 0;
    auto alloc = [&](size_t bytes) {
        void* p = ws + off;
        off = (off + bytes + 255) & ~(size_t)255;
        return p;
    };
    int*   cntmat = (int*)  alloc((size_t)NCH * NBK * 4);  // 1.22 MB
    int*   bsum   = (int*)  alloc((size_t)NBK * 4);
    int*   boffs  = (int*)  alloc((size_t)(NBK + 1) * 4);
    int*   rowptr = (int*)  alloc((size_t)(NN + 1) * 4);
    int*   csr    = (int*)  alloc((size_t)NE * 4);         // 6.4 MB
    float* dinv   = (float*)alloc((size_t)NN * 4);
    unsigned short* wtbuf = (unsigned short*)alloc((size_t)4 * 4096 * 2);  // 32 KB
    unsigned short* bufA = (unsigned short*)alloc((size_t)NN * D * 2);    // 12.8 MB
    unsigned short* bufB = (unsigned short*)alloc((size_t)NN * D * 2);    // 12.8 MB
    int*   ebuf   = (int*)bufA;  // binning scratch; dead before bufA first written

    k_hist          <<<NCH, 512, 0, stream>>>(dstv, cntmat);
    k_colsum_rowscan<<<NBK, 512, 0, stream>>>(cntmat, bsum);
    k_scan_prepw    <<<3, 1024, 0, stream>>>(bsum, boffs, W1, W2, wtbuf);
    k_bin           <<<NCH, 512, 0, stream>>>(srcv, dstv, cntmat, boffs, ebuf);
    k_csrdeg        <<<NBK, 512, 0, stream>>>(boffs, ebuf, rowptr, dinv, csr);

    const int MMB = (NN + 63) / 64;   // 1563

    // layer 1 mm: g1 = bf16((x @ W1) * dinv) -> bufA
    k_mm_mfma<<<MMB, 256, 0, stream>>>(x, wtbuf, dinv, (uint4*)bufA);
    // fused: h1 = relu(agg(g1)) (LDS tile) ; g2 = bf16((h1 @ W2) * dinv) -> bufB
    k_aggmm<<<MMB, 512, 0, stream>>>(rowptr, csr, (const uint4*)bufA, dinv, b1,
                                     wtbuf + 8192, (uint4*)bufB);
    // layer 2 agg: h2 = agg(g2) -> bufA
    k_agg2<<<NN / 32, 256, 0, stream>>>(rowptr, csr, (const uint4*)bufB, dinv, b2,
                                        (uint4*)bufA);
    k_poolhead<<<NG, 64, 0, stream>>>(bufA, batch, lw1, lb1, lw2, lb2, out);
}

// Round 14
// 212.413 us; speedup vs baseline: 1.0846x; 1.0663x over previous
//
#include <hip/hip_runtime.h>

static constexpr int NN  = 100000;   // nodes
static constexpr int NE  = 1600000;  // edges
static constexpr int NG  = 1000;     // graphs
static constexpr int D   = 64;       // D_IN = D_HID
static constexpr int DH  = 32;       // head hidden
static constexpr int DO  = 8;        // out dim
static constexpr int BKT = 128;      // nodes per bucket (7 bits)
static constexpr int NBK = (NN + BKT - 1) / BKT;     // 782
static constexpr int CAP = 2560;     // fixed bucket capacity (mean 2048, 11 sigma)
static constexpr int CHUNK = 4096;                   // edges per chunk block
static constexpr int NCH = (NE + CHUNK - 1) / CHUNK; // 391

typedef __attribute__((ext_vector_type(8))) short bf16x8;
typedef __attribute__((ext_vector_type(4))) float f32x4;

// ---- bf16 helpers (bit-level; values here are never NaN/inf) ----
__device__ __forceinline__ float b2f(unsigned short u) {
    return __uint_as_float(((unsigned int)u) << 16);
}
__device__ __forceinline__ unsigned short f2b(float f) {   // round-to-nearest-even
    unsigned int u = __float_as_uint(f);
    u += 0x7FFFu + ((u >> 16) & 1u);
    return (unsigned short)(u >> 16);
}
__device__ __forceinline__ uint4 pack8(const unsigned short* h) {
    uint4 u;
    u.x = (unsigned)h[0] | ((unsigned)h[1] << 16);
    u.y = (unsigned)h[2] | ((unsigned)h[3] << 16);
    u.z = (unsigned)h[4] | ((unsigned)h[5] << 16);
    u.w = (unsigned)h[6] | ((unsigned)h[7] << 16);
    return u;
}

// block 0: zero the 782 bucket cursors; blocks 1,2: split W1/W2 into transposed
// bf16 hi/lo.  No other prep dependencies — runs first.
__global__ __launch_bounds__(256) void
k_prepw(const float* __restrict__ W1, const float* __restrict__ W2,
        unsigned short* __restrict__ wtbuf, int* __restrict__ gcur) {
    int t = threadIdx.x;
    if (blockIdx.x == 0) {
        for (int b = t; b < NBK; b += 256) gcur[b] = 0;
    } else {
        const float* W = (blockIdx.x == 2) ? W2 : W1;
        unsigned short* WtHi = wtbuf + (size_t)(blockIdx.x - 1) * 8192;
        unsigned short* WtLo = WtHi + 4096;
        int n = t >> 2, k0 = (t & 3) * 16;
        unsigned short hi[16], lo[16];
#pragma unroll
        for (int i = 0; i < 16; ++i) {
            float v = W[(k0 + i) * 64 + n];
            hi[i] = f2b(v);
            lo[i] = f2b(v - b2f(hi[i]));
        }
        ((uint4*)WtHi)[n * 8 + (t & 3) * 2]     = pack8(hi);
        ((uint4*)WtHi)[n * 8 + (t & 3) * 2 + 1] = pack8(hi + 8);
        ((uint4*)WtLo)[n * 8 + (t & 3) * 2]     = pack8(lo);
        ((uint4*)WtLo)[n * 8 + (t & 3) * 2 + 1] = pack8(lo + 8);
    }
}

// fixed-capacity binning: LDS per-chunk count -> one global atomic per
// (block,bucket) reserves a range inside bucket b's [b*CAP, b*CAP+CAP) slab.
// packed edge = src*128 + (dst & 127).
__global__ __launch_bounds__(512) void
k_bin(const int* __restrict__ src, const int* __restrict__ dst,
      int* __restrict__ gcur, int* __restrict__ ebuf) {
    __shared__ int lcnt[NBK];
    __shared__ int lbase[NBK];
    int t = threadIdx.x;
    long base = (long)blockIdx.x * CHUNK;
    for (int b = t; b < NBK; b += 512) lcnt[b] = 0;
    __syncthreads();
    int pk[8], bk[8], of[8];
#pragma unroll
    for (int j = 0; j < 8; ++j) {
        long i = base + j * 512 + t;
        if (i < NE) {
            int d = dst[i];
            bk[j] = d >> 7;
            pk[j] = src[i] * BKT + (d & (BKT - 1));
            of[j] = atomicAdd(&lcnt[bk[j]], 1);
        } else bk[j] = -1;
    }
    __syncthreads();
    for (int b = t; b < NBK; b += 512) {
        int c = lcnt[b];
        if (c) lbase[b] = b * CAP + atomicAdd(&gcur[b], c);
    }
    __syncthreads();
#pragma unroll
    for (int j = 0; j < 8; ++j)
        if (bk[j] >= 0) ebuf[lbase[bk[j]] + of[j]] = pk[j];
}

// per-bucket: LDS histogram of local idx -> rowptr/deg/dinv, exact CSR scatter
// into the bucket's fixed slab of csr.
__global__ __launch_bounds__(512) void
k_csrdeg(const int* __restrict__ gcur, const int* __restrict__ ebuf,
         int* __restrict__ rowptr, int* __restrict__ deg, float* __restrict__ dinv,
         int* __restrict__ csr) {
    __shared__ int hist[BKT];
    __shared__ int sc[BKT];
    __shared__ int lcur[BKT];
    int b = blockIdx.x, t = threadIdx.x;
    if (t < BKT) hist[t] = 0;
    __syncthreads();
    int beg = b * CAP;
    int end = beg + gcur[b];
    for (int e = beg + t; e < end; e += 512)
        atomicAdd(&hist[ebuf[e] & (BKT - 1)], 1);
    __syncthreads();
    if (t < BKT) sc[t] = hist[t];
    __syncthreads();
    for (int o = 1; o < BKT; o <<= 1) {
        int a = (t < BKT && t >= o) ? sc[t - o] : 0;
        __syncthreads();
        if (t < BKT) sc[t] += a;
        __syncthreads();
    }
    int v0 = b * BKT;
    if (t < BKT) {
        int v = v0 + t;
        if (v < NN) {
            int excl = beg + sc[t] - hist[t];
            rowptr[v] = excl;
            deg[v]    = hist[t];
            dinv[v]   = rsqrtf((float)(hist[t] + 1));
            lcur[t]   = excl;
        }
    }
    __syncthreads();
    for (int e = beg + t; e < end; e += 512) {
        int p = ebuf[e];
        int slot = atomicAdd(&lcur[p & (BKT - 1)], 1);
        csr[slot] = p >> 7;
    }
}

// MFMA matmul: out[n][:] = bf16(dinv[n] * (A[n][:] @ W)), 64 nodes/block.
// Split-bf16: A@W = Ahi·Whi + Ahi·Wlo + Alo·Whi — ~f32 accurate (f32 A input).
__global__ __launch_bounds__(256) void
k_mm_mfma(const float* __restrict__ Ain, const unsigned short* __restrict__ wt,
          const float* __restrict__ dinv, uint4* __restrict__ out) {
    __shared__ unsigned short smem[4 * 64 * 72];   // 36864 B
    unsigned short* Ahi  = smem;
    unsigned short* Alo  = smem + 4608;
    unsigned short* WtHi = smem + 9216;
    unsigned short* WtLo = smem + 13824;
    int t = threadIdx.x;
    int r = t >> 2, cc = t & 3, c0 = cc * 16;
    long n0 = (long)blockIdx.x * 64;
    {   // stage Wt (hi/lo), coalesced
        const uint4* H = (const uint4*)wt;
        const uint4* L = (const uint4*)(wt + 4096);
        uint4* dh = (uint4*)&WtHi[r * 72 + c0];
        uint4* dl = (uint4*)&WtLo[r * 72 + c0];
        dh[0] = H[r * 8 + cc * 2]; dh[1] = H[r * 8 + cc * 2 + 1];
        dl[0] = L[r * 8 + cc * 2]; dl[1] = L[r * 8 + cc * 2 + 1];
    }
    {   // stage A (convert + split)
        long n = n0 + r; if (n >= NN) n = NN - 1;
        const float4* X = (const float4*)Ain;
        unsigned short hi[16], lo[16];
#pragma unroll
        for (int i = 0; i < 4; ++i) {
            float4 v = X[n * 16 + cc * 4 + i];
            float vv[4] = {v.x, v.y, v.z, v.w};
#pragma unroll
            for (int j = 0; j < 4; ++j) {
                unsigned short h = f2b(vv[j]);
                hi[i * 4 + j] = h;
                lo[i * 4 + j] = f2b(vv[j] - b2f(h));
            }
        }
        uint4* dh = (uint4*)&Ahi[r * 72 + c0];
        uint4* dl = (uint4*)&Alo[r * 72 + c0];
        dh[0] = pack8(hi); dh[1] = pack8(hi + 8);
        dl[0] = pack8(lo); dl[1] = pack8(lo + 8);
    }
    __syncthreads();
    int lane = t & 63, w = t >> 6;
    int q = lane >> 4, m = lane & 15;
    f32x4 acc[4] = {{0.f,0.f,0.f,0.f},{0.f,0.f,0.f,0.f},{0.f,0.f,0.f,0.f},{0.f,0.f,0.f,0.f}};
#pragma unroll
    for (int s = 0; s < 2; ++s) {
        int ko = s * 32 + q * 8;
        bf16x8 ah = *(const bf16x8*)&Ahi[(w * 16 + m) * 72 + ko];
        bf16x8 al = *(const bf16x8*)&Alo[(w * 16 + m) * 72 + ko];
#pragma unroll
        for (int c = 0; c < 4; ++c) {
            bf16x8 bh = *(const bf16x8*)&WtHi[(c * 16 + m) * 72 + ko];
            bf16x8 bl = *(const bf16x8*)&WtLo[(c * 16 + m) * 72 + ko];
            acc[c] = __builtin_amdgcn_mfma_f32_16x16x32_bf16(ah, bh, acc[c], 0, 0, 0);
            acc[c] = __builtin_amdgcn_mfma_f32_16x16x32_bf16(ah, bl, acc[c], 0, 0, 0);
            acc[c] = __builtin_amdgcn_mfma_f32_16x16x32_bf16(al, bh, acc[c], 0, 0, 0);
        }
    }
    __syncthreads();
    float* Ct = (float*)smem;   // 64 x 68 f32 tile (overlaps dead A/Wt)
#pragma unroll
    for (int c = 0; c < 4; ++c)
#pragma unroll
        for (int rr = 0; rr < 4; ++rr)
            Ct[(w * 16 + q * 4 + rr) * 68 + c * 16 + m] = acc[c][rr];
    __syncthreads();
    {
        long n = n0 + r;
        if (n < NN) {
            float dv = dinv[n];
            unsigned short ob[16];
#pragma unroll
            for (int i = 0; i < 4; ++i) {
                float4 v = *(const float4*)&Ct[r * 68 + c0 + i * 4];
                ob[i * 4 + 0] = f2b(v.x * dv); ob[i * 4 + 1] = f2b(v.y * dv);
                ob[i * 4 + 2] = f2b(v.z * dv); ob[i * 4 + 3] = f2b(v.w * dv);
            }
            out[n * 8 + cc * 2]     = pack8(ob);
            out[n * 8 + cc * 2 + 1] = pack8(ob + 8);
        }
    }
}

// Fused agg(layer1, relu) -> LDS h1 tile -> MFMA @ W2 -> g2.  64 nodes/block.
__global__ __launch_bounds__(512) void
k_aggmm(const int* __restrict__ rowptr, const int* __restrict__ deg,
        const int* __restrict__ csr,
        const uint4* __restrict__ g4, const float* __restrict__ dinv,
        const float* __restrict__ bias, const unsigned short* __restrict__ wt,
        uint4* __restrict__ out) {
    __shared__ unsigned short smem[3 * 4608];   // Ahi | WtHi | WtLo (27648 B)
    unsigned short* Ahi  = smem;
    unsigned short* WtHi = smem + 4608;
    unsigned short* WtLo = smem + 9216;
    int t = threadIdx.x;
    long n0 = (long)blockIdx.x * 64;
    if (t < 256) {   // stage W2 (hi/lo)
        int r = t >> 2, cc = t & 3, c0 = cc * 16;
        const uint4* H = (const uint4*)wt;
        const uint4* L = (const uint4*)(wt + 4096);
        uint4* dh = (uint4*)&WtHi[r * 72 + c0];
        uint4* dl = (uint4*)&WtLo[r * 72 + c0];
        dh[0] = H[r * 8 + cc * 2]; dh[1] = H[r * 8 + cc * 2 + 1];
        dl[0] = L[r * 8 + cc * 2]; dl[1] = L[r * 8 + cc * 2 + 1];
    }
    // phase 1: aggregate 8 waves x 8 nodes
    int lane = t & 63, w = t >> 6;
    int fg = lane & 7, slot = lane >> 3;
    int ln = w * 8 + slot;                 // local node 0..63
    long v = n0 + ln;
    int vc = (v < NN) ? (int)v : NN - 1;
    int beg = rowptr[vc];
    int len = (v < NN) ? deg[vc] : 0;
    int lmax = len;
    lmax = max(lmax, __shfl_xor(lmax, 8));
    lmax = max(lmax, __shfl_xor(lmax, 16));
    lmax = max(lmax, __shfl_xor(lmax, 32));
    float acc[8];
    {
        uint4 sv = g4[(long)vc * 8 + fg];
        if (v >= NN) { sv.x = sv.y = sv.z = sv.w = 0u; }
        acc[0] = __uint_as_float(sv.x << 16); acc[1] = __uint_as_float(sv.x & 0xFFFF0000u);
        acc[2] = __uint_as_float(sv.y << 16); acc[3] = __uint_as_float(sv.y & 0xFFFF0000u);
        acc[4] = __uint_as_float(sv.z << 16); acc[5] = __uint_as_float(sv.z & 0xFFFF0000u);
        acc[6] = __uint_as_float(sv.w << 16); acc[7] = __uint_as_float(sv.w & 0xFFFF0000u);
    }
    for (int e = 0; e < lmax; e += 8) {
#pragma unroll
        for (int j = 0; j < 8; ++j) {
            int ee = e + j;
            float m = (ee < len) ? 1.f : 0.f;
            int idx = beg + ((ee < len) ? ee : 0);
            int srcn = csr[idx];
            uint4 a = g4[(long)srcn * 8 + fg];
            acc[0] += m * __uint_as_float(a.x << 16);
            acc[1] += m * __uint_as_float(a.x & 0xFFFF0000u);
            acc[2] += m * __uint_as_float(a.y << 16);
            acc[3] += m * __uint_as_float(a.y & 0xFFFF0000u);
            acc[4] += m * __uint_as_float(a.z << 16);
            acc[5] += m * __uint_as_float(a.z & 0xFFFF0000u);
            acc[6] += m * __uint_as_float(a.w << 16);
            acc[7] += m * __uint_as_float(a.w & 0xFFFF0000u);
        }
    }
    {
        float dv = dinv[vc];
        unsigned short ob[8];
#pragma unroll
        for (int k = 0; k < 8; ++k) {
            float x = fmaxf(acc[k] * dv + bias[fg * 8 + k], 0.f);   // h1 = relu(..)
            ob[k] = f2b(x);
        }
        *(uint4*)&Ahi[ln * 72 + fg * 8] = pack8(ob);
    }
    __syncthreads();
    // phase 2: MFMA h1 @ W2 (8 waves: row strip = (w&3)*16, 2 col-blocks each)
    int q = lane >> 4, m = lane & 15;
    int rs = (w & 3) * 16;
    int cb0 = (w >> 2) * 2;
    f32x4 c2[2] = {{0.f,0.f,0.f,0.f},{0.f,0.f,0.f,0.f}};
#pragma unroll
    for (int s = 0; s < 2; ++s) {
        int ko = s * 32 + q * 8;
        bf16x8 ah = *(const bf16x8*)&Ahi[(rs + m) * 72 + ko];
#pragma unroll
        for (int c = 0; c < 2; ++c) {
            bf16x8 bh = *(const bf16x8*)&WtHi[((cb0 + c) * 16 + m) * 72 + ko];
            bf16x8 bl = *(const bf16x8*)&WtLo[((cb0 + c) * 16 + m) * 72 + ko];
            c2[c] = __builtin_amdgcn_mfma_f32_16x16x32_bf16(ah, bh, c2[c], 0, 0, 0);
            c2[c] = __builtin_amdgcn_mfma_f32_16x16x32_bf16(ah, bl, c2[c], 0, 0, 0);
        }
    }
    __syncthreads();
    float* Ct = (float*)smem;   // 64 x 68 f32 = 17408 B (overlaps dead A/Wt)
#pragma unroll
    for (int c = 0; c < 2; ++c)
#pragma unroll
        for (int rr = 0; rr < 4; ++rr)
            Ct[(rs + q * 4 + rr) * 68 + (cb0 + c) * 16 + m] = c2[c][rr];
    __syncthreads();
    {
        int r = t >> 3, c8 = (t & 7) * 8;
        long n = n0 + r;
        if (n < NN) {
            float dv = dinv[n];
            float4 a = *(const float4*)&Ct[r * 68 + c8];
            float4 b = *(const float4*)&Ct[r * 68 + c8 + 4];
            unsigned short ob[8] = {f2b(a.x * dv), f2b(a.y * dv), f2b(a.z * dv), f2b(a.w * dv),
                                    f2b(b.x * dv), f2b(b.y * dv), f2b(b.z * dv), f2b(b.w * dv)};
            out[n * 8 + (t & 7)] = pack8(ob);
        }
    }
}

// CSR pull aggregation on bf16 rows (layer 2, no relu), unroll 8.
__global__ __launch_bounds__(256) void
k_agg2(const int* __restrict__ rowptr, const int* __restrict__ deg,
       const int* __restrict__ csr,
       const uint4* __restrict__ g4, const float* __restrict__ dinv,
       const float* __restrict__ bias, uint4* __restrict__ out4) {
    int t = threadIdx.x;
    int lane = t & 63;
    int fg = lane & 7;
    int slot = lane >> 3;
    int wid = blockIdx.x * 4 + (t >> 6);
    int v = wid * 8 + slot;      // 12500 * 8 == NN exactly
    int beg = rowptr[v];
    int len = deg[v];
    int lmax = len;
    lmax = max(lmax, __shfl_xor(lmax, 8));
    lmax = max(lmax, __shfl_xor(lmax, 16));
    lmax = max(lmax, __shfl_xor(lmax, 32));
    float acc[8];
    {
        uint4 sv = g4[(long)v * 8 + fg];
        acc[0] = __uint_as_float(sv.x << 16); acc[1] = __uint_as_float(sv.x & 0xFFFF0000u);
        acc[2] = __uint_as_float(sv.y << 16); acc[3] = __uint_as_float(sv.y & 0xFFFF0000u);
        acc[4] = __uint_as_float(sv.z << 16); acc[5] = __uint_as_float(sv.z & 0xFFFF0000u);
        acc[6] = __uint_as_float(sv.w << 16); acc[7] = __uint_as_float(sv.w & 0xFFFF0000u);
    }
    for (int e = 0; e < lmax; e += 8) {
#pragma unroll
        for (int j = 0; j < 8; ++j) {
            int ee = e + j;
            float m = (ee < len) ? 1.f : 0.f;
            int idx = beg + ((ee < len) ? ee : 0);
            int srcn = csr[idx];
            uint4 a = g4[(long)srcn * 8 + fg];
            acc[0] += m * __uint_as_float(a.x << 16);
            acc[1] += m * __uint_as_float(a.x & 0xFFFF0000u);
            acc[2] += m * __uint_as_float(a.y << 16);
            acc[3] += m * __uint_as_float(a.y & 0xFFFF0000u);
            acc[4] += m * __uint_as_float(a.z << 16);
            acc[5] += m * __uint_as_float(a.z & 0xFFFF0000u);
            acc[6] += m * __uint_as_float(a.w << 16);
            acc[7] += m * __uint_as_float(a.w & 0xFFFF0000u);
        }
    }
    float dv = dinv[v];
    unsigned short ob[8];
#pragma unroll
    for (int k = 0; k < 8; ++k)
        ob[k] = f2b(acc[k] * dv + bias[fg * 8 + k]);
    out4[(long)v * 8 + fg] = pack8(ob);
}

// fused mean-pool + MLP head, one wave per graph, zero atomics (batch sorted)
__global__ void k_poolhead(const unsigned short* __restrict__ h,
                           const int* __restrict__ batch,
                           const float* __restrict__ lw1, const float* __restrict__ lb1,
                           const float* __restrict__ lw2, const float* __restrict__ lb2,
                           float* __restrict__ out) {
    __shared__ float pl[D];
    __shared__ float z[DH];
    int g = blockIdx.x;
    int t = threadIdx.x;  // 64, lane = dim
    int lo = 0, hi = NN;
    while (lo < hi) { int m = (lo + hi) >> 1; if (batch[m] < g) lo = m + 1; else hi = m; }
    int lb = lo;
    hi = NN;
    while (lo < hi) { int m = (lo + hi) >> 1; if (batch[m] < g + 1) lo = m + 1; else hi = m; }
    int ub = lo;
    float s = 0.f;
    int n = lb;
    for (; n + 4 <= ub; n += 4) {
        float a0 = b2f(h[(long)(n + 0) * D + t]);
        float a1 = b2f(h[(long)(n + 1) * D + t]);
        float a2 = b2f(h[(long)(n + 2) * D + t]);
        float a3 = b2f(h[(long)(n + 3) * D + t]);
        s += a0 + a1 + a2 + a3;
    }
    for (; n < ub; ++n) s += b2f(h[(long)n * D + t]);
    pl[t] = s / fmaxf((float)(ub - lb), 1.0f);
    __syncthreads();
    if (t < DH) {
        float a = lb1[t];
#pragma unroll
        for (int k = 0; k < D; ++k) a += pl[k] * lw1[k * DH + t];
        z[t] = fmaxf(a, 0.f);
    }
    __syncthreads();
    if (t < DO) {
        float a = lb2[t];
#pragma unroll
        for (int j = 0; j < DH; ++j) a += z[j] * lw2[j * DO + t];
        out[g * DO + t] = a;
    }
}

extern "C" void kernel_launch(void* const* d_in, const int* in_sizes, int n_in,
                              void* d_out, int out_size, void* d_ws, size_t ws_size,
                              hipStream_t stream) {
    const float* x    = (const float*)d_in[0];
    const int*   ei   = (const int*)  d_in[1];
    const int*   batch= (const int*)  d_in[2];
    const float* W1   = (const float*)d_in[3];
    const float* b1   = (const float*)d_in[4];
    const float* W2   = (const float*)d_in[5];
    const float* b2   = (const float*)d_in[6];
    const float* lw1  = (const float*)d_in[7];
    const float* lb1  = (const float*)d_in[8];
    const float* lw2  = (const float*)d_in[9];
    const float* lb2  = (const float*)d_in[10];
    float* out = (float*)d_out;

    const int* srcv = ei;        // edge_index[0]
    const int* dstv = ei + NE;   // edge_index[1]

    char* ws = (char*)d_ws;
    size_t off = 0;
    auto alloc = [&](size_t bytes) {
        void* p = ws + off;
        off = (off + bytes + 255) & ~(size_t)255;
        return p;
    };
    int*   gcur   = (int*)  alloc((size_t)NBK * 4);
    int*   rowptr = (int*)  alloc((size_t)NN * 4);
    int*   deg    = (int*)  alloc((size_t)NN * 4);
    int*   csr    = (int*)  alloc((size_t)NBK * CAP * 4);  // 8.0 MB slabbed
    float* dinv   = (float*)alloc((size_t)NN * 4);
    unsigned short* wtbuf = (unsigned short*)alloc((size_t)4 * 4096 * 2);  // 32 KB
    unsigned short* bufA = (unsigned short*)alloc((size_t)NN * D * 2);    // 12.8 MB
    unsigned short* bufB = (unsigned short*)alloc((size_t)NN * D * 2);    // 12.8 MB
    int*   ebuf   = (int*)bufA;  // binning scratch (8.0 MB); dead before bufA written

    k_prepw <<<3, 256, 0, stream>>>(W1, W2, wtbuf, gcur);
    k_bin   <<<NCH, 512, 0, stream>>>(srcv, dstv, gcur, ebuf);
    k_csrdeg<<<NBK, 512, 0, stream>>>(gcur, ebuf, rowptr, deg, dinv, csr);

    const int MMB = (NN + 63) / 64;   // 1563

    // layer 1 mm: g1 = bf16((x @ W1) * dinv) -> bufA
    k_mm_mfma<<<MMB, 256, 0, stream>>>(x, wtbuf, dinv, (uint4*)bufA);
    // fused: h1 = relu(agg(g1)) (LDS tile) ; g2 = bf16((h1 @ W2) * dinv) -> bufB
    k_aggmm<<<MMB, 512, 0, stream>>>(rowptr, deg, csr, (const uint4*)bufA, dinv, b1,
                                     wtbuf + 8192, (uint4*)bufB);
    // layer 2 agg: h2 = agg(g2) -> bufA
    k_agg2<<<NN / 32, 256, 0, stream>>>(rowptr, deg, csr, (const uint4*)bufB, dinv, b2,
                                        (uint4*)bufA);
    k_poolhead<<<NG, 64, 0, stream>>>(bufA, batch, lw1, lb1, lw2, lb2, out);
}